// Round 14
// baseline (302.570 us; speedup 1.0000x reference)
//
#include <hip/hip_runtime.h>
#include <hip/hip_bf16.h>

#define TSEQ 2048
#define TBZ  32
#define TDIM 1024
#define NLS  8

typedef __attribute__((ext_vector_type(8))) short bf16x8;
typedef __attribute__((ext_vector_type(4))) float f32x4;

__device__ inline unsigned int pk2(float lo, float hi) {
    __hip_bfloat162 h = __float22bfloat162_rn(make_float2(lo, hi)); // v_cvt_pk_bf16_f32
    return *reinterpret_cast<const unsigned int*>(&h);
}

__device__ inline void gload_lds16(const void* g, void* l) {
    __builtin_amdgcn_global_load_lds(
        (const __attribute__((address_space(1))) unsigned int*)g,
        (__attribute__((address_space(3))) unsigned int*)l,
        16, 0, 0);
}

// ---------- dispatch 1: W conv + FIRST-needed A chunks + flag zero ----------
// Blocks [0,256): W f32->bf16. Blocks [256,512): tiles {0,4} x 32 b x 4
// quarter-blocks of 64 rows. Block 512: zero the 256 flags.
__global__ __launch_bounds__(256) void conv_pre(
    const float* __restrict__ x, const int* __restrict__ lang_ids,
    const float* __restrict__ W,
    unsigned short* __restrict__ xb, unsigned short* __restrict__ wb,
    int* __restrict__ flags)
{
    const int bid = blockIdx.x;
    if (bid == 512) {
        if (threadIdx.x < 256) flags[threadIdx.x] = 0;
        return;
    }
    if (bid < 256) {                               // W part
        const int total = NLS * TDIM * TDIM / 8;
        for (int i = bid * 256 + threadIdx.x; i < total; i += 256 * 256) {
            const float* src = W + (long)i * 8;
            f32x4 v0 = *(const f32x4*)(src);
            f32x4 v1 = *(const f32x4*)(src + 4);
            uint4 o;
            o.x = pk2(v0.x, v0.y); o.y = pk2(v0.z, v0.w);
            o.z = pk2(v1.x, v1.y); o.w = pk2(v1.z, v1.w);
            *(uint4*)(wb + (long)i * 8) = o;
        }
        return;
    }
    // first chunks: i in [0,256): chunk c=i>>2 (b=c>>1, mt=(c&1)*4), quarter q
    const int i  = bid - 256;
    const int c  = i >> 2;
    const int q  = i & 3;
    const int b  = c >> 1;
    const int gid = 8 - lang_ids[b];
    if (!(gid >= 1 && gid <= 8)) return;
    const int srow0 = (c & 1) * 4 * 256 + q * 64;
    for (int r = 0; r < 64; ++r) {
        const int s = srow0 + r;
        const float* sp = x + ((long)s * TBZ + b) * TDIM + threadIdx.x * 4;
        f32x4 v = *(const f32x4*)sp;
        uint2 o; o.x = pk2(v.x, v.y); o.y = pk2(v.z, v.w);
        *(uint2*)(xb + ((long)b * TSEQ + s) * TDIM + threadIdx.x * 4) = o;
    }
}

// ---------- dispatch 2: r10 GEMM + fused next-m-tile A conversion ----------
// GEMM core byte-identical to round 10 (158 us, verified 5x).
// r13 BUG FIXED: CONVQ's base row double-counted strip (s0 + global-tile*256).
// Now sbase_ = mt*256 (mt is the GLOBAL m-tile index). Row cover audit:
// conv_pre: tiles 0,4 (rows 0-255, 1024-1279); strip0 CONVQ: tiles 1-3
// (rows 256-1023); strip1 CONVQ: tiles 5-7 (rows 1280-2047). Disjoint,
// complete, in-bounds (max 2047).
//  * it==0 (mtl<3), after P8's VMC(6): CONVQ converts this block's nt-quarter
//    (64 rows) of global tile strip*4+mtl+1. 48 VMEM ops/lane; max
//    outstanding 62 <= 63; batch lies between two VMC(6) points -> it1-P4's
//    VMC(6) drains it; NO vmcnt count changes.
//  * it==1 (mtl<3), after P4's VMC(6): tid 0 agent-RELEASE fetch_add on
//    flags[(b*2+strip)*4+mtl+1] (release -> L2 writeback publishes stores).
//  * it==7 (mtl<3), loop top (first cross-tile stage is it7-P2): waves spin
//    RELAXED to 4, then one agent-ACQUIRE load (invalidate).
// Deadlock-impossible: grid 256 = 1 block/CU -> all resident; producers
// reach it1 unconditionally before any consumer's it7; forward DAG.

#define BAR __builtin_amdgcn_s_barrier()
#define SB0 __builtin_amdgcn_sched_barrier(0)
#define VMC(n) asm volatile("s_waitcnt vmcnt(" #n ")" ::: "memory")
#define KAo(kv) (((kv) & 1023) + (((kv) >> 10) << 18))
#define KBo(kv) ((kv) & 1023)

__global__ __launch_bounds__(512, 2) void mapper_gemm8p(
    const float* __restrict__ x,                // [s][b][d] f32 (conv src + passthrough)
    unsigned short* xb,                          // [b][s][d] bf16 (read + conv dst)
    const int* __restrict__ lang_ids,
    const unsigned short* __restrict__ wb,      // [e][out][in] bf16
    const float* __restrict__ bias,
    int* flags,
    float* __restrict__ out)
{
    // XCD-chunked bijective swizzle: 256 = 8 * 32; nt fastest.
    const int p  = blockIdx.x;
    const int l  = (p & 7) * 32 + (p >> 3);
    const int b  = l >> 3;
    const int strip = (l >> 2) & 1;             // 4 m-tiles per strip
    const int nt = l & 3;
    const int s0 = strip * 1024;
    const int e0 = nt * 256;
    const int tid = threadIdx.x;

    const int gid = 8 - lang_ids[b];
    if (!(gid >= 1 && gid <= 8)) {
        // passthrough: out[s0..s0+1024][b][e0..e0+256] = x[...]
        const f32x4* xs = (const f32x4*)x;
        f32x4*       os = (f32x4*)out;
        const int rs4 = TBZ * TDIM / 4;
        for (int i = tid; i < 1024 * 256 / 4; i += 512) {
            int r = i >> 6;
            int c = i & 63;
            long idx = (long)(s0 + r) * rs4 + b * (TDIM / 4) + (e0 >> 2) + c;
            os[idx] = xs[idx];
        }
        return;
    }
    const int eb = gid - 1;

    __shared__ uint4 ldsbuf[131072 / 16];
    char* ldsc = (char*)ldsbuf;

    const int lane = tid & 63;
    const int wave = tid >> 6;
    const int wr   = wave >> 2;
    const int wc   = wave & 3;
    const int fr   = lane & 15;
    const int fq   = lane >> 4;
    const int fr7  = fr & 7;

    const unsigned short* Aab = xb + (long)b  * TSEQ * TDIM + (long)s0 * TDIM;
    const unsigned short* __restrict__ Bbb = wb + (long)eb * TDIM * TDIM + (long)e0 * TDIM;

    const int L    = lane;
    const int lch8 = ((L & 7) ^ (L >> 3)) * 8;   // pre-inverse-swizzled global chunk
    const int ldA0 = wave * 2048 + L * 16;
    const unsigned short* aG[2][2];
    const unsigned short* bG[2][2];
    #pragma unroll
    for (int j = 0; j < 2; ++j) {
        const int rr = wave * 16 + j * 8 + (L >> 3);
        #pragma unroll
        for (int mh = 0; mh < 2; ++mh)
            aG[j][mh] = Aab + ((rr >> 6) * 128 + mh * 64 + (rr & 63)) * TDIM + lch8;
        #pragma unroll
        for (int nh = 0; nh < 2; ++nh)
            bG[j][nh] = Bbb + ((rr >> 5) * 64 + nh * 32 + (rr & 31)) * TDIM + lch8;
    }

#define STAGE_A(slot, mh, kofs) do { \
    gload_lds16(aG[0][mh] + (kofs), ldsc + (slot)*32768 + (mh)*16384 + ldA0); \
    gload_lds16(aG[1][mh] + (kofs), ldsc + (slot)*32768 + (mh)*16384 + ldA0 + 1024); \
} while (0)
#define STAGE_B(slot, nh, kofs) do { \
    gload_lds16(bG[0][nh] + (kofs), ldsc + 65536 + (slot)*32768 + (nh)*16384 + ldA0); \
    gload_lds16(bG[1][nh] + (kofs), ldsc + 65536 + (slot)*32768 + (nh)*16384 + ldA0 + 1024); \
} while (0)
#define RD_A(slot, mh) do { \
    _Pragma("unroll") for (int ml = 0; ml < 4; ++ml) { \
        const int rr = wr * 64 + ml * 16 + fr; \
        _Pragma("unroll") for (int kk = 0; kk < 2; ++kk) \
            af[ml][kk] = *(const bf16x8*)(ldsc + (slot)*32768 + (mh)*16384 + rr*128 + (((kk*4+fq) ^ fr7) << 4)); \
    } } while (0)
#define RD_B(slot, nh, br) do { \
    _Pragma("unroll") for (int nl = 0; nl < 2; ++nl) { \
        const int rr = wc * 32 + nl * 16 + fr; \
        _Pragma("unroll") for (int kk = 0; kk < 2; ++kk) \
            br[nl][kk] = *(const bf16x8*)(ldsc + 65536 + (slot)*32768 + (nh)*16384 + rr*128 + (((kk*4+fq) ^ fr7) << 4)); \
    } } while (0)
// Swapped operands (C^T): col=lane&15 -> s_local, row=(lane>>4)*4+j -> e_local.
#define MM(mh, nh, br) do { \
    __builtin_amdgcn_s_setprio(1); \
    _Pragma("unroll") for (int ml = 0; ml < 4; ++ml) \
    _Pragma("unroll") for (int nl = 0; nl < 2; ++nl) \
    _Pragma("unroll") for (int kk = 0; kk < 2; ++kk) \
        acc[(mh)*4+ml][(nh)*2+nl] = __builtin_amdgcn_mfma_f32_16x16x32_bf16( \
            br[nl][kk], af[ml][kk], acc[(mh)*4+ml][(nh)*2+nl], 0, 0, 0); \
    __builtin_amdgcn_s_setprio(0); \
} while (0)

// Convert this block's nt-quarter (64 rows) of GLOBAL m-tile (mt).
// 8 waves x 8 rows; per lane per row: 4 f32x4 loads + 2 uint4 stores.
#define CONVQ(mt) do { \
    const int sbase_ = (mt) * 256 + nt * 64 + wave * 8; \
    _Pragma("unroll 1") for (int r_ = 0; r_ < 8; ++r_) { \
        const int s_ = sbase_ + r_; \
        const float* sp_ = x + ((long)s_ * TBZ + b) * TDIM + lane * 16; \
        f32x4 a0_ = *(const f32x4*)(sp_);      f32x4 a1_ = *(const f32x4*)(sp_ + 4); \
        f32x4 a2_ = *(const f32x4*)(sp_ + 8);  f32x4 a3_ = *(const f32x4*)(sp_ + 12); \
        uint4 o0_, o1_; \
        o0_.x = pk2(a0_.x, a0_.y); o0_.y = pk2(a0_.z, a0_.w); \
        o0_.z = pk2(a1_.x, a1_.y); o0_.w = pk2(a1_.z, a1_.w); \
        o1_.x = pk2(a2_.x, a2_.y); o1_.y = pk2(a2_.z, a2_.w); \
        o1_.z = pk2(a3_.x, a3_.y); o1_.w = pk2(a3_.z, a3_.w); \
        unsigned short* dp_ = xb + ((long)b * TSEQ + s_) * TDIM + lane * 16; \
        *(uint4*)(dp_)     = o0_; \
        *(uint4*)(dp_ + 8) = o1_; \
    } \
} while (0)

    f32x4 acc[8][4];
    #pragma unroll
    for (int m = 0; m < 8; ++m)
        #pragma unroll
        for (int n = 0; n < 4; ++n)
            acc[m][n] = (f32x4){0.f, 0.f, 0.f, 0.f};

    bf16x8 af[4][2], bf0[2][2], bf1[2][2];

    const int flbase = (b * 2 + strip) * 4;

    // prologue: tile0 all 4 halves + tile1 {Amh0,Bnh0,Bnh1}
    STAGE_A(0, 0, 0);  STAGE_B(0, 0, 0);  STAGE_B(0, 1, 0);  STAGE_A(0, 1, 0);
    STAGE_A(1, 0, 64); STAGE_B(1, 0, 64); STAGE_B(1, 1, 64);
    VMC(6); BAR; SB0;

    const int cs  = lane & 15;          // s_local
    const int eqb = (lane >> 4) << 2;   // e_local base (4 consecutive)

    #pragma unroll 1
    for (int mtl = 0; mtl < 4; ++mtl) {
        #pragma unroll 1
        for (int it = 0; it < 8; ++it) {
            // consumer spin: next m-tile must be converted before the first
            // cross-tile stage (it7-P2's A@kn)
            if (it == 7 && mtl < 3) {
                if (lane == 0) {
                    while (__hip_atomic_load(&flags[flbase + mtl + 1],
                                             __ATOMIC_RELAXED,
                                             __HIP_MEMORY_SCOPE_AGENT) < 4)
                        __builtin_amdgcn_s_sleep(2);
                }
                __hip_atomic_load(&flags[flbase + mtl + 1],
                                  __ATOMIC_ACQUIRE, __HIP_MEMORY_SCOPE_AGENT);
                SB0;
            }
            const int kva = mtl * 1024 + it * 128;
            const int kb = kva + 64;
            const int kn = kva + 128;   // wraps into next m-tile after it=7
            const int km = kva + 192;
            // P1
            RD_A(0, 0); RD_B(0, 0, bf0); STAGE_A(1, 1, KAo(kb));
            BAR; SB0; MM(0, 0, bf0); BAR; SB0;
            // P2
            RD_B(0, 1, bf1); STAGE_A(0, 0, KAo(kn));
            BAR; SB0; MM(0, 1, bf1); BAR; SB0;
            // P3
            RD_A(0, 1); STAGE_B(0, 0, KBo(kn));
            BAR; SB0; MM(1, 0, bf0); BAR; SB0;
            // P4
            STAGE_B(0, 1, KBo(kn));
            BAR; SB0; MM(1, 1, bf1); VMC(6);
            // producer flag: conv batch issued at it0-P8 has drained here
            if (it == 1 && mtl < 3 && tid == 0)
                __hip_atomic_fetch_add(&flags[flbase + mtl + 1], 1,
                                       __ATOMIC_RELEASE, __HIP_MEMORY_SCOPE_AGENT);
            BAR; SB0;
            // P5
            RD_A(1, 0); RD_B(1, 0, bf0); STAGE_A(0, 1, KAo(kn));
            BAR; SB0; MM(0, 0, bf0); BAR; SB0;
            // P6
            RD_B(1, 1, bf1); STAGE_A(1, 0, KAo(km));
            BAR; SB0; MM(0, 1, bf1); BAR; SB0;
            // P7
            RD_A(1, 1); STAGE_B(1, 0, KBo(km));
            BAR; SB0; MM(1, 0, bf0); BAR; SB0;
            // P8
            STAGE_B(1, 1, KBo(km));
            BAR; SB0; MM(1, 1, bf1); VMC(6); SB0;
            // fused conversion of next tile's quarter (between VMC(6) points)
            if (it == 0 && mtl < 3) { CONVQ(strip * 4 + mtl + 1); }
            BAR; SB0;
        }

        // epilogue: 32 dwordx4 stores; drain overlaps the bridge prefetch
        const int sb = s0 + mtl * 256 + wr * 128;
        #pragma unroll
        for (int n = 0; n < 4; ++n) {
            const int e = e0 + wc * 64 + n * 16 + eqb;
            const f32x4 bv4 = *(const f32x4*)&bias[eb * TDIM + e];
            #pragma unroll
            for (int m = 0; m < 8; ++m) {
                const int s = sb + m * 16 + cs;
                *(f32x4*)&out[(long)s * (TBZ * TDIM) + b * TDIM + e] = acc[m][n] + bv4;
            }
        }
        #pragma unroll
        for (int m = 0; m < 8; ++m)
            #pragma unroll
            for (int n = 0; n < 4; ++n)
                acc[m][n] = (f32x4){0.f, 0.f, 0.f, 0.f};
    }
#undef STAGE_A
#undef STAGE_B
#undef RD_A
#undef RD_B
#undef MM
#undef CONVQ
}

// ---------- fallback: round-1 fused kernel ----------
__device__ inline unsigned short f2bf(float f) {
    union { float f; unsigned int u; } v; v.f = f;
    unsigned int r = v.u + 0x7fffu + ((v.u >> 16) & 1u);
    return (unsigned short)(r >> 16);
}
constexpr int FLDS = 40;

__global__ __launch_bounds__(256) void mapper_fused(
    const float* __restrict__ x, const int* __restrict__ lang_ids,
    const float* __restrict__ W, const float* __restrict__ bias,
    float* __restrict__ out)
{
    const int bid = blockIdx.x;
    const int b   = bid >> 7;
    const int t   = bid & 127;
    const int mt  = t >> 3;
    const int nt  = t & 7;
    const int s0  = mt * 128;
    const int e0  = nt * 128;
    const int tid = threadIdx.x;

    const int gid = 8 - lang_ids[b];
    const bool active = (gid >= 1) && (gid <= 8);
    int eb = gid - 1; eb = eb < 0 ? 0 : (eb > 7 ? 7 : eb);

    if (!active) {
        const f32x4* xs = (const f32x4*)x;
        f32x4*       os = (f32x4*)out;
        const int rs4 = TBZ * TDIM / 4;
        for (int i = tid; i < 128 * 128 / 4; i += 256) {
            int r = i >> 5, c = i & 31;
            long idx = (long)(s0 + r) * rs4 + b * (TDIM / 4) + (e0 >> 2) + c;
            os[idx] = xs[idx];
        }
        return;
    }

    __shared__ unsigned short As[128 * FLDS];
    __shared__ unsigned short Bs[128 * FLDS];
    const float* __restrict__ Wb = W + (long)eb * TDIM * TDIM;

    const int lane = tid & 63;
    const int wave = tid >> 6;
    const int wrr  = wave >> 1;
    const int wcc  = wave & 1;

    f32x4 acc[4][4];
    #pragma unroll
    for (int m = 0; m < 4; ++m)
        #pragma unroll
        for (int n = 0; n < 4; ++n)
            acc[m][n] = (f32x4){0.f, 0.f, 0.f, 0.f};

    const int rg = tid >> 3;
    const int cg = tid & 7;
    const int fr = lane & 15;
    const int fo = (lane >> 4) * 8;

    for (int k0 = 0; k0 < TDIM; k0 += 32) {
        __syncthreads();
        #pragma unroll
        for (int pp = 0; pp < 4; ++pp) {
            const int r = rg + pp * 32;
            f32x4 av = *(const f32x4*)(x  + (long)(s0 + r) * (TBZ * TDIM) + b * TDIM + k0 + cg * 4);
            f32x4 bv = *(const f32x4*)(Wb + (long)(e0 + r) * TDIM + k0 + cg * 4);
            unsigned int alo = (unsigned)f2bf(av.x) | ((unsigned)f2bf(av.y) << 16);
            unsigned int ahi = (unsigned)f2bf(av.z) | ((unsigned)f2bf(av.w) << 16);
            unsigned int blo = (unsigned)f2bf(bv.x) | ((unsigned)f2bf(bv.y) << 16);
            unsigned int bhi = (unsigned)f2bf(bv.z) | ((unsigned)f2bf(bv.w) << 16);
            *(uint2*)&As[r * FLDS + cg * 4] = make_uint2(alo, ahi);
            *(uint2*)&Bs[r * FLDS + cg * 4] = make_uint2(blo, bhi);
        }
        __syncthreads();

        bf16x8 af2[4], bfm[4];
        #pragma unroll
        for (int m = 0; m < 4; ++m)
            af2[m] = *(const bf16x8*)&As[(wrr * 64 + m * 16 + fr) * FLDS + fo];
        #pragma unroll
        for (int n = 0; n < 4; ++n)
            bfm[n] = *(const bf16x8*)&Bs[(wcc * 64 + n * 16 + fr) * FLDS + fo];
        #pragma unroll
        for (int m = 0; m < 4; ++m)
            #pragma unroll
            for (int n = 0; n < 4; ++n)
                acc[m][n] = __builtin_amdgcn_mfma_f32_16x16x32_bf16(af2[m], bfm[n], acc[m][n], 0, 0, 0);
    }

    const int cr = lane >> 4;
    const int cc2 = lane & 15;
    #pragma unroll
    for (int n = 0; n < 4; ++n) {
        const int e  = e0 + wcc * 64 + n * 16 + cc2;
        const float bv = bias[eb * TDIM + e];
        #pragma unroll
        for (int m = 0; m < 4; ++m) {
            #pragma unroll
            for (int j = 0; j < 4; ++j) {
                const int s = s0 + wrr * 64 + m * 16 + cr * 4 + j;
                out[(long)s * (TBZ * TDIM) + b * TDIM + e] = acc[m][n][j] + bv;
            }
        }
    }
}

extern "C" void kernel_launch(void* const* d_in, const int* in_sizes, int n_in,
                              void* d_out, int out_size, void* d_ws, size_t ws_size,
                              hipStream_t stream) {
    const float* x        = (const float*)d_in[0];
    const int*   lang_ids = (const int*)d_in[1];
    const float* W        = (const float*)d_in[2];
    const float* bias     = (const float*)d_in[3];
    float*       out      = (float*)d_out;

    const size_t xbytes = (size_t)TSEQ * TBZ * TDIM * 2;   // 128 MiB
    const size_t wbytes = (size_t)NLS * TDIM * TDIM * 2;   // 16 MiB
    const size_t fbytes = 1024;                            // 256 flags

    if (ws_size >= xbytes + wbytes + fbytes) {
        unsigned short* xbp = (unsigned short*)d_ws;
        unsigned short* wbp = (unsigned short*)((char*)d_ws + xbytes);
        int*            flg = (int*)((char*)d_ws + xbytes + wbytes);
        conv_pre<<<513, 256, 0, stream>>>(x, lang_ids, W, xbp, wbp, flg);
        mapper_gemm8p<<<256, 512, 0, stream>>>(x, xbp, lang_ids, wbp, bias, flg, out);
    } else {
        mapper_fused<<<TBZ * 16 * 8, 256, 0, stream>>>(x, lang_ids, W, bias, out);
    }
}

// Round 15
// 259.542 us; speedup vs baseline: 1.1658x; 1.1658x over previous
//
#include <hip/hip_runtime.h>
#include <hip/hip_bf16.h>

#define TSEQ 2048
#define TBZ  32
#define TDIM 1024
#define NLS  8

typedef __attribute__((ext_vector_type(8))) short bf16x8;
typedef __attribute__((ext_vector_type(4))) float f32x4;

__device__ inline unsigned int pk2(float lo, float hi) {
    __hip_bfloat162 h = __float22bfloat162_rn(make_float2(lo, hi)); // v_cvt_pk_bf16_f32
    return *reinterpret_cast<const unsigned int*>(&h);
}

__device__ inline void gload_lds16(const void* g, void* l) {
    __builtin_amdgcn_global_load_lds(
        (const __attribute__((address_space(1))) unsigned int*)g,
        (__attribute__((address_space(3))) unsigned int*)l,
        16, 0, 0);
}

// ---------- pass 1: merged conversion, one dispatch, block-uniform roles ----
__global__ __launch_bounds__(256) void conv_all(
    const float* __restrict__ x, const int* __restrict__ lang_ids,
    const float* __restrict__ W,
    unsigned short* __restrict__ xb, unsigned short* __restrict__ wb,
    float* __restrict__ out)
{
    const int bid = blockIdx.x;
    if (bid < 256) {                               // W part: 1M chunks of 8
        const int total = NLS * TDIM * TDIM / 8;
        for (int i = bid * 256 + threadIdx.x; i < total; i += 256 * 256) {
            const float* src = W + (long)i * 8;
            f32x4 v0 = *(const f32x4*)(src);
            f32x4 v1 = *(const f32x4*)(src + 4);
            uint4 o;
            o.x = pk2(v0.x, v0.y); o.y = pk2(v0.z, v0.w);
            o.z = pk2(v1.x, v1.y); o.w = pk2(v1.z, v1.w);
            *(uint4*)(wb + (long)i * 8) = o;
        }
        return;
    }
    // x part: 2048 blocks = 32 b x 64 s-chunks of 32 rows, block-uniform b
    const int xb_id = bid - 256;
    const int b     = xb_id >> 6;
    const int s0c   = (xb_id & 63) * 32;
    const int gid   = 8 - lang_ids[b];
    const bool active = (gid >= 1) && (gid <= 8);

    for (int i = threadIdx.x; i < 32 * 128; i += 256) {
        const int ls = i >> 7;
        const int d8 = i & 127;
        const int s  = s0c + ls;
        const float* src = x + ((long)s * TBZ + b) * TDIM + d8 * 8;
        f32x4 v0 = *(const f32x4*)(src);
        f32x4 v1 = *(const f32x4*)(src + 4);
        if (active) {
            uint4 o;
            o.x = pk2(v0.x, v0.y); o.y = pk2(v0.z, v0.w);
            o.z = pk2(v1.x, v1.y); o.w = pk2(v1.z, v1.w);
            *(uint4*)(xb + ((long)b * TSEQ + s) * TDIM + d8 * 8) = o;
        } else {
            float* dst = out + ((long)s * TBZ + b) * TDIM + d8 * 8;
            *(f32x4*)(dst)     = v0;
            *(f32x4*)(dst + 4) = v1;
        }
    }
}

// ---------- pass 2: persistent 256x256 8-phase bf16 GEMM, 4 m-tiles/block ----
// Best verified configuration (rounds 6/8/9/10: GEMM 158-164 us, 5x pass).
// 8-phase schedule, both-sides XOR swizzle (0 bank conflicts), counted
// VMC(6) (never 0 in loop), bridge prefetch across m-tiles, C^T epilogue
// with dwordx4 stores, rolled loops (#pragma unroll 1), sched_barrier(0)
// pins phase boundaries; compiler emits fine-grained lgkmcnt.
// Known residuals (measured, not fixed at source level): ~11.9k cy/iter vs
// m201's 6.6k on the same skeleton (6 schedule probes null/regressed);
// conversion/GEMM overlap blocked by in-order vmcnt at 1 block/CU (r13/r14).

#define BAR __builtin_amdgcn_s_barrier()
#define SB0 __builtin_amdgcn_sched_barrier(0)
#define VMC(n) asm volatile("s_waitcnt vmcnt(" #n ")" ::: "memory")
#define KAo(kv) (((kv) & 1023) + (((kv) >> 10) << 18))
#define KBo(kv) ((kv) & 1023)

__global__ __launch_bounds__(512, 2) void mapper_gemm8p(
    const unsigned short* __restrict__ xb,      // [b][s][d] bf16
    const int* __restrict__ lang_ids,
    const unsigned short* __restrict__ wb,      // [e][out][in] bf16
    const float* __restrict__ bias,
    float* __restrict__ out)
{
    // XCD-chunked bijective swizzle: 256 = 8 * 32; nt fastest so the 4
    // blocks sharing an A strip-panel are consecutive on one XCD.
    const int p  = blockIdx.x;
    const int l  = (p & 7) * 32 + (p >> 3);
    const int b  = l >> 3;
    const int strip = (l >> 2) & 1;             // 4 m-tiles per strip
    const int nt = l & 3;
    const int s0 = strip * 1024;
    const int e0 = nt * 256;
    const int tid = threadIdx.x;

    const int gid = 8 - lang_ids[b];
    if (!(gid >= 1 && gid <= 8)) return;        // conv_all wrote passthrough
    const int eb = gid - 1;

    __shared__ uint4 ldsbuf[131072 / 16];
    char* ldsc = (char*)ldsbuf;

    const int lane = tid & 63;
    const int wave = tid >> 6;
    const int wr   = wave >> 2;
    const int wc   = wave & 3;
    const int fr   = lane & 15;
    const int fq   = lane >> 4;
    const int fr7  = fr & 7;

    const unsigned short* __restrict__ Aab = xb + (long)b  * TSEQ * TDIM + (long)s0 * TDIM;
    const unsigned short* __restrict__ Bbb = wb + (long)eb * TDIM * TDIM + (long)e0 * TDIM;

    const int L    = lane;
    const int lch8 = ((L & 7) ^ (L >> 3)) * 8;   // pre-inverse-swizzled global chunk
    const int ldA0 = wave * 2048 + L * 16;
    const unsigned short* aG[2][2];
    const unsigned short* bG[2][2];
    #pragma unroll
    for (int j = 0; j < 2; ++j) {
        const int rr = wave * 16 + j * 8 + (L >> 3);
        #pragma unroll
        for (int mh = 0; mh < 2; ++mh)
            aG[j][mh] = Aab + ((rr >> 6) * 128 + mh * 64 + (rr & 63)) * TDIM + lch8;
        #pragma unroll
        for (int nh = 0; nh < 2; ++nh)
            bG[j][nh] = Bbb + ((rr >> 5) * 64 + nh * 32 + (rr & 31)) * TDIM + lch8;
    }

#define STAGE_A(slot, mh, kofs) do { \
    gload_lds16(aG[0][mh] + (kofs), ldsc + (slot)*32768 + (mh)*16384 + ldA0); \
    gload_lds16(aG[1][mh] + (kofs), ldsc + (slot)*32768 + (mh)*16384 + ldA0 + 1024); \
} while (0)
#define STAGE_B(slot, nh, kofs) do { \
    gload_lds16(bG[0][nh] + (kofs), ldsc + 65536 + (slot)*32768 + (nh)*16384 + ldA0); \
    gload_lds16(bG[1][nh] + (kofs), ldsc + 65536 + (slot)*32768 + (nh)*16384 + ldA0 + 1024); \
} while (0)
#define RD_A(slot, mh) do { \
    _Pragma("unroll") for (int ml = 0; ml < 4; ++ml) { \
        const int rr = wr * 64 + ml * 16 + fr; \
        _Pragma("unroll") for (int kk = 0; kk < 2; ++kk) \
            af[ml][kk] = *(const bf16x8*)(ldsc + (slot)*32768 + (mh)*16384 + rr*128 + (((kk*4+fq) ^ fr7) << 4)); \
    } } while (0)
#define RD_B(slot, nh, br) do { \
    _Pragma("unroll") for (int nl = 0; nl < 2; ++nl) { \
        const int rr = wc * 32 + nl * 16 + fr; \
        _Pragma("unroll") for (int kk = 0; kk < 2; ++kk) \
            br[nl][kk] = *(const bf16x8*)(ldsc + 65536 + (slot)*32768 + (nh)*16384 + rr*128 + (((kk*4+fq) ^ fr7) << 4)); \
    } } while (0)
// Swapped operands (C^T): col=lane&15 -> s_local, row=(lane>>4)*4+j -> e_local.
#define MM(mh, nh, br) do { \
    __builtin_amdgcn_s_setprio(1); \
    _Pragma("unroll") for (int ml = 0; ml < 4; ++ml) \
    _Pragma("unroll") for (int nl = 0; nl < 2; ++nl) \
    _Pragma("unroll") for (int kk = 0; kk < 2; ++kk) \
        acc[(mh)*4+ml][(nh)*2+nl] = __builtin_amdgcn_mfma_f32_16x16x32_bf16( \
            br[nl][kk], af[ml][kk], acc[(mh)*4+ml][(nh)*2+nl], 0, 0, 0); \
    __builtin_amdgcn_s_setprio(0); \
} while (0)

    f32x4 acc[8][4];
    #pragma unroll
    for (int m = 0; m < 8; ++m)
        #pragma unroll
        for (int n = 0; n < 4; ++n)
            acc[m][n] = (f32x4){0.f, 0.f, 0.f, 0.f};

    bf16x8 af[4][2], bf0[2][2], bf1[2][2];

    // prologue: tile0 all 4 halves + tile1 {Amh0,Bnh0,Bnh1}
    STAGE_A(0, 0, 0);  STAGE_B(0, 0, 0);  STAGE_B(0, 1, 0);  STAGE_A(0, 1, 0);
    STAGE_A(1, 0, 64); STAGE_B(1, 0, 64); STAGE_B(1, 1, 64);
    VMC(6); BAR; SB0;

    const int cs  = lane & 15;          // s_local
    const int eqb = (lane >> 4) << 2;   // e_local base (4 consecutive)

    #pragma unroll 1
    for (int mtl = 0; mtl < 4; ++mtl) {
        #pragma unroll 1
        for (int it = 0; it < 8; ++it) {
            const int kva = mtl * 1024 + it * 128;
            const int kb = kva + 64;
            const int kn = kva + 128;   // wraps into next m-tile after it=7
            const int km = kva + 192;
            // P1
            RD_A(0, 0); RD_B(0, 0, bf0); STAGE_A(1, 1, KAo(kb));
            BAR; SB0; MM(0, 0, bf0); BAR; SB0;
            // P2
            RD_B(0, 1, bf1); STAGE_A(0, 0, KAo(kn));
            BAR; SB0; MM(0, 1, bf1); BAR; SB0;
            // P3
            RD_A(0, 1); STAGE_B(0, 0, KBo(kn));
            BAR; SB0; MM(1, 0, bf0); BAR; SB0;
            // P4
            STAGE_B(0, 1, KBo(kn));
            BAR; SB0; MM(1, 1, bf1); VMC(6); BAR; SB0;
            // P5
            RD_A(1, 0); RD_B(1, 0, bf0); STAGE_A(0, 1, KAo(kn));
            BAR; SB0; MM(0, 0, bf0); BAR; SB0;
            // P6
            RD_B(1, 1, bf1); STAGE_A(1, 0, KAo(km));
            BAR; SB0; MM(0, 1, bf1); BAR; SB0;
            // P7
            RD_A(1, 1); STAGE_B(1, 0, KBo(km));
            BAR; SB0; MM(1, 0, bf0); BAR; SB0;
            // P8
            STAGE_B(1, 1, KBo(km));
            BAR; SB0; MM(1, 1, bf1); VMC(6); BAR; SB0;
        }

        // epilogue: 32 dwordx4 stores; drain overlaps the bridge prefetch
        const int sb = s0 + mtl * 256 + wr * 128;
        #pragma unroll
        for (int n = 0; n < 4; ++n) {
            const int e = e0 + wc * 64 + n * 16 + eqb;
            const f32x4 bv4 = *(const f32x4*)&bias[eb * TDIM + e];
            #pragma unroll
            for (int m = 0; m < 8; ++m) {
                const int s = sb + m * 16 + cs;
                *(f32x4*)&out[(long)s * (TBZ * TDIM) + b * TDIM + e] = acc[m][n] + bv4;
            }
        }
        #pragma unroll
        for (int m = 0; m < 8; ++m)
            #pragma unroll
            for (int n = 0; n < 4; ++n)
                acc[m][n] = (f32x4){0.f, 0.f, 0.f, 0.f};
    }
#undef STAGE_A
#undef STAGE_B
#undef RD_A
#undef RD_B
#undef MM
}

// ---------- fallback: round-1 fused kernel ----------
__device__ inline unsigned short f2bf(float f) {
    union { float f; unsigned int u; } v; v.f = f;
    unsigned int r = v.u + 0x7fffu + ((v.u >> 16) & 1u);
    return (unsigned short)(r >> 16);
}
constexpr int FLDS = 40;

__global__ __launch_bounds__(256) void mapper_fused(
    const float* __restrict__ x, const int* __restrict__ lang_ids,
    const float* __restrict__ W, const float* __restrict__ bias,
    float* __restrict__ out)
{
    const int bid = blockIdx.x;
    const int b   = bid >> 7;
    const int t   = bid & 127;
    const int mt  = t >> 3;
    const int nt  = t & 7;
    const int s0  = mt * 128;
    const int e0  = nt * 128;
    const int tid = threadIdx.x;

    const int gid = 8 - lang_ids[b];
    const bool active = (gid >= 1) && (gid <= 8);
    int eb = gid - 1; eb = eb < 0 ? 0 : (eb > 7 ? 7 : eb);

    if (!active) {
        const f32x4* xs = (const f32x4*)x;
        f32x4*       os = (f32x4*)out;
        const int rs4 = TBZ * TDIM / 4;
        for (int i = tid; i < 128 * 128 / 4; i += 256) {
            int r = i >> 5, c = i & 31;
            long idx = (long)(s0 + r) * rs4 + b * (TDIM / 4) + (e0 >> 2) + c;
            os[idx] = xs[idx];
        }
        return;
    }

    __shared__ unsigned short As[128 * FLDS];
    __shared__ unsigned short Bs[128 * FLDS];
    const float* __restrict__ Wb = W + (long)eb * TDIM * TDIM;

    const int lane = tid & 63;
    const int wave = tid >> 6;
    const int wrr  = wave >> 1;
    const int wcc  = wave & 1;

    f32x4 acc[4][4];
    #pragma unroll
    for (int m = 0; m < 4; ++m)
        #pragma unroll
        for (int n = 0; n < 4; ++n)
            acc[m][n] = (f32x4){0.f, 0.f, 0.f, 0.f};

    const int rg = tid >> 3;
    const int cg = tid & 7;
    const int fr = lane & 15;
    const int fo = (lane >> 4) * 8;

    for (int k0 = 0; k0 < TDIM; k0 += 32) {
        __syncthreads();
        #pragma unroll
        for (int pp = 0; pp < 4; ++pp) {
            const int r = rg + pp * 32;
            f32x4 av = *(const f32x4*)(x  + (long)(s0 + r) * (TBZ * TDIM) + b * TDIM + k0 + cg * 4);
            f32x4 bv = *(const f32x4*)(Wb + (long)(e0 + r) * TDIM + k0 + cg * 4);
            unsigned int alo = (unsigned)f2bf(av.x) | ((unsigned)f2bf(av.y) << 16);
            unsigned int ahi = (unsigned)f2bf(av.z) | ((unsigned)f2bf(av.w) << 16);
            unsigned int blo = (unsigned)f2bf(bv.x) | ((unsigned)f2bf(bv.y) << 16);
            unsigned int bhi = (unsigned)f2bf(bv.z) | ((unsigned)f2bf(bv.w) << 16);
            *(uint2*)&As[r * FLDS + cg * 4] = make_uint2(alo, ahi);
            *(uint2*)&Bs[r * FLDS + cg * 4] = make_uint2(blo, bhi);
        }
        __syncthreads();

        bf16x8 af2[4], bfm[4];
        #pragma unroll
        for (int m = 0; m < 4; ++m)
            af2[m] = *(const bf16x8*)&As[(wrr * 64 + m * 16 + fr) * FLDS + fo];
        #pragma unroll
        for (int n = 0; n < 4; ++n)
            bfm[n] = *(const bf16x8*)&Bs[(wcc * 64 + n * 16 + fr) * FLDS + fo];
        #pragma unroll
        for (int m = 0; m < 4; ++m)
            #pragma unroll
            for (int n = 0; n < 4; ++n)
                acc[m][n] = __builtin_amdgcn_mfma_f32_16x16x32_bf16(af2[m], bfm[n], acc[m][n], 0, 0, 0);
    }

    const int cr = lane >> 4;
    const int cc2 = lane & 15;
    #pragma unroll
    for (int n = 0; n < 4; ++n) {
        const int e  = e0 + wcc * 64 + n * 16 + cc2;
        const float bv = bias[eb * TDIM + e];
        #pragma unroll
        for (int m = 0; m < 4; ++m) {
            #pragma unroll
            for (int j = 0; j < 4; ++j) {
                const int s = s0 + wrr * 64 + m * 16 + cr * 4 + j;
                out[(long)s * (TBZ * TDIM) + b * TDIM + e] = acc[m][n][j] + bv;
            }
        }
    }
}

extern "C" void kernel_launch(void* const* d_in, const int* in_sizes, int n_in,
                              void* d_out, int out_size, void* d_ws, size_t ws_size,
                              hipStream_t stream) {
    const float* x        = (const float*)d_in[0];
    const int*   lang_ids = (const int*)d_in[1];
    const float* W        = (const float*)d_in[2];
    const float* bias     = (const float*)d_in[3];
    float*       out      = (float*)d_out;

    const size_t xbytes = (size_t)TSEQ * TBZ * TDIM * 2;   // 128 MiB
    const size_t wbytes = (size_t)NLS * TDIM * TDIM * 2;   // 16 MiB

    if (ws_size >= xbytes + wbytes) {
        unsigned short* xbp = (unsigned short*)d_ws;
        unsigned short* wbp = (unsigned short*)((char*)d_ws + xbytes);
        conv_all<<<2304, 256, 0, stream>>>(x, lang_ids, W, xbp, wbp, out);
        mapper_gemm8p<<<256, 512, 0, stream>>>(xbp, lang_ids, wbp, bias, out);
    } else {
        mapper_fused<<<TBZ * 16 * 8, 256, 0, stream>>>(x, lang_ids, W, bias, out);
    }
}